// Round 6
// baseline (276.063 us; speedup 1.0000x reference)
//
#include <hip/hip_runtime.h>
#include <hip/hip_bf16.h>
#include <math.h>

#define DIM 100
#define BN_EPS 1e-5f

using short8v = __attribute__((ext_vector_type(8))) short;
using f32x4v  = __attribute__((ext_vector_type(4))) float;

__device__ __forceinline__ short f2bf(float f) {
    unsigned u = __float_as_uint(f);
    unsigned r = (u + 0x7fffu + ((u >> 16) & 1u)) >> 16;
    return (short)r;
}

// ============ phase 1: row-degree histogram ============
__global__ void k_hist(const int* __restrict__ ei, int* __restrict__ hist, int E, int NE) {
    int i = blockIdx.x * blockDim.x + threadIdx.x;
    int stride = gridDim.x * blockDim.x;
    int twoE = 2 * E;
    for (; i < twoE; i += stride) {
        int slot = ((i < E) ? 0 : NE) + ei[i];
        atomicAdd(&hist[slot], 1);
    }
}

// ============ phase 2: parallel exclusive scan (+ dinv fused) ============
__global__ void k_scanA(const int* __restrict__ hist, int* __restrict__ base,
                        int* __restrict__ blocksum, float* __restrict__ dinv, int n) {
    __shared__ int lsum[256];
    int tid = threadIdx.x;
    int i0 = blockIdx.x * 1024 + tid * 4;
    int v0 = (i0 + 0 < n) ? hist[i0 + 0] : 0;
    int v1 = (i0 + 1 < n) ? hist[i0 + 1] : 0;
    int v2 = (i0 + 2 < n) ? hist[i0 + 2] : 0;
    int v3 = (i0 + 3 < n) ? hist[i0 + 3] : 0;
    if (i0 + 0 < n) dinv[i0 + 0] = v0 > 0 ? rsqrtf((float)v0) : 0.f;
    if (i0 + 1 < n) dinv[i0 + 1] = v1 > 0 ? rsqrtf((float)v1) : 0.f;
    if (i0 + 2 < n) dinv[i0 + 2] = v2 > 0 ? rsqrtf((float)v2) : 0.f;
    if (i0 + 3 < n) dinv[i0 + 3] = v3 > 0 ? rsqrtf((float)v3) : 0.f;
    int s = v0 + v1 + v2 + v3;
    lsum[tid] = s;
    __syncthreads();
    for (int off = 1; off < 256; off <<= 1) {
        int t = (tid >= off) ? lsum[tid - off] : 0;
        __syncthreads();
        lsum[tid] += t;
        __syncthreads();
    }
    int excl = lsum[tid] - s;
    if (i0 + 0 < n) base[i0 + 0] = excl;
    if (i0 + 1 < n) base[i0 + 1] = excl + v0;
    if (i0 + 2 < n) base[i0 + 2] = excl + v0 + v1;
    if (i0 + 3 < n) base[i0 + 3] = excl + v0 + v1 + v2;
    if (tid == 255) blocksum[blockIdx.x] = lsum[255];
}

__global__ void k_scanB(const int* __restrict__ blocksum, int* __restrict__ blockoff, int nb) {
    __shared__ int s[256];
    int tid = threadIdx.x;
    int v = (tid < nb) ? blocksum[tid] : 0;
    s[tid] = v;
    __syncthreads();
    for (int off = 1; off < 256; off <<= 1) {
        int t = (tid >= off) ? s[tid - off] : 0;
        __syncthreads();
        s[tid] += t;
        __syncthreads();
    }
    if (tid < nb) blockoff[tid] = s[tid] - v;
}

__global__ void k_scanC(int* __restrict__ base, int* __restrict__ cursor,
                        const int* __restrict__ blockoff, int n, int total) {
    int i0 = blockIdx.x * 1024 + threadIdx.x * 4;
    int off = blockoff[blockIdx.x];
#pragma unroll
    for (int j = 0; j < 4; ++j) {
        int i = i0 + j;
        if (i < n) { int v = base[i] + off; base[i] = v; cursor[i] = v; }
    }
    if (blockIdx.x == 0 && threadIdx.x == 0) base[n] = total;
}

// ============ phase 3: scatter edges into CSR order ============
__global__ void k_scatter(const int* __restrict__ ei, const int* __restrict__ et,
                          int* __restrict__ cursor, unsigned int* __restrict__ packed,
                          int E, int NE) {
    int i = blockIdx.x * blockDim.x + threadIdx.x;
    int stride = gridDim.x * blockDim.x;
    int twoE = 2 * E;
    for (; i < twoE; i += stride) {
        int r = ei[i];
        int c = ei[twoE + i];
        int t = et[i];
        int slot = ((i < E) ? 0 : NE) + r;
        int pos = atomicAdd(&cursor[slot], 1);
        packed[pos] = (unsigned int)c | ((unsigned int)t << 17);
    }
}

// ============ W fragment pre-pack + rel matmul (fused, both weight-only) ============
#define WPREP_THREADS (3 * 4 * 7 * 64)
__global__ void k_wrel(const float* __restrict__ w_in, const float* __restrict__ w_out,
                       const float* __restrict__ w_loop, short* __restrict__ wfrag,
                       const float* __restrict__ rel, const float* __restrict__ w_rel,
                       float* __restrict__ out2, int nbW, int relTotal4) {
    int tid = threadIdx.x;
    if ((int)blockIdx.x < nbW) {
        int g = blockIdx.x * 256 + tid;
        if (g >= WPREP_THREADS) return;
        int lane = g & 63;
        int rest = g >> 6;
        int nt = rest % 7;
        int ks = (rest / 7) % 4;
        int src = rest / 28;
        const float* W = (src == 0) ? w_in : (src == 1) ? w_out : w_loop;
        int col = nt * 16 + (lane & 15);
        short8v frag;
#pragma unroll
        for (int j = 0; j < 8; ++j) {
            int k = ks * 32 + ((lane >> 4) << 3) + j;
            float v = (k < DIM && col < DIM) ? W[k * DIM + col] : 0.f;
            frag[j] = f2bf(v);
        }
        reinterpret_cast<short8v*>(wfrag)[g] = frag;
    } else {
        int i = (blockIdx.x - nbW) * 256 + tid;
        if (i >= relTotal4) return;
        int r = i / 25;
        int d = (i - r * 25) * 4;
        const float* a = rel + r * DIM;
        float4 acc = make_float4(0.f, 0.f, 0.f, 0.f);
#pragma unroll 4
        for (int k = 0; k < DIM; ++k) {
            float av = a[k];
            float4 w = *reinterpret_cast<const float4*>(w_rel + k * DIM + d);
            acc.x += av * w.x; acc.y += av * w.y; acc.z += av * w.z; acc.w += av * w.w;
        }
        *reinterpret_cast<float4*>(out2 + r * DIM + d) = acc;
    }
}

// ============ FUSED: edge gather-aggregate (LDS, bf16) + MFMA GEMM + column stats ===========
// One block per 16 output rows. Phase 1: 4 waves x 8 CSR rows (16 in-dir + 16 out-dir),
// results stored to LDS as bf16 in A-fragment order (row stride 136 shorts = 272B:
// 17x16B granules -> <=2-way bank aliasing = free). Phase 2: 84 MFMAs split across
// waves by N-tile; fused column stats; store out.
#define LROW 136
__global__ __launch_bounds__(256) void k_fused(
    const unsigned int* __restrict__ packed, const int* __restrict__ base,
    const float* __restrict__ x, const float* __restrict__ rel,
    const float* __restrict__ dinv, const float* __restrict__ loop_rel,
    const short* __restrict__ wfrag, float* __restrict__ out,
    float* __restrict__ colsum, float* __restrict__ colsumsq, int NE) {
    __shared__ short Ain[16][LROW];
    __shared__ short Aout[16][LROW];
    __shared__ float cs[112], cq[112];

    int tid = threadIdx.x;
    if (tid < 112) { cs[tid] = 0.f; cq[tid] = 0.f; }
    int w = tid >> 6;
    int lane = tid & 63;
    int sub = lane >> 5;           // 0: even edges, 1: odd edges
    int slot = lane & 31;
    int rbase = blockIdx.x * 16;

    // ---------- phase 1: aggregate 8 CSR rows per wave ----------
    for (int i = 0; i < 8; ++i) {
        int idx = w * 8 + i;       // 0..31: 0-15 in-dir, 16-31 out-dir
        int lr = idx & 15;
        bool isOut = idx >= 16;
        int row = rbase + lr;
        short* dst = (isOut ? Aout[lr] : Ain[lr]);
        if (row < NE) {
            int crow = (isOut ? NE : 0) + row;
            int d = (slot < 25) ? slot * 4 : 96;
            int dbase = isOut ? NE : 0;
            float dr = dinv[crow];
            int s = base[crow], e = base[crow + 1];
            float4 a0 = make_float4(0.f, 0.f, 0.f, 0.f);
            float4 a1 = make_float4(0.f, 0.f, 0.f, 0.f);
            int j = s + sub;
            for (; j + 2 < e; j += 4) {
                unsigned int p0 = packed[j];
                unsigned int p1 = packed[j + 2];
                int c0 = (int)(p0 & 0x1FFFFu), t0 = (int)(p0 >> 17);
                int c1 = (int)(p1 & 0x1FFFFu), t1 = (int)(p1 >> 17);
                float n0 = dr * dinv[dbase + c0];
                float n1 = dr * dinv[dbase + c1];
                float4 xv0 = *reinterpret_cast<const float4*>(x + c0 * DIM + d);
                float4 rv0 = *reinterpret_cast<const float4*>(rel + t0 * DIM + d);
                float4 xv1 = *reinterpret_cast<const float4*>(x + c1 * DIM + d);
                float4 rv1 = *reinterpret_cast<const float4*>(rel + t1 * DIM + d);
                a0.x += xv0.x * rv0.x * n0; a0.y += xv0.y * rv0.y * n0;
                a0.z += xv0.z * rv0.z * n0; a0.w += xv0.w * rv0.w * n0;
                a1.x += xv1.x * rv1.x * n1; a1.y += xv1.y * rv1.y * n1;
                a1.z += xv1.z * rv1.z * n1; a1.w += xv1.w * rv1.w * n1;
            }
            if (j < e) {
                unsigned int p0 = packed[j];
                int c0 = (int)(p0 & 0x1FFFFu), t0 = (int)(p0 >> 17);
                float n0 = dr * dinv[dbase + c0];
                float4 xv0 = *reinterpret_cast<const float4*>(x + c0 * DIM + d);
                float4 rv0 = *reinterpret_cast<const float4*>(rel + t0 * DIM + d);
                a0.x += xv0.x * rv0.x * n0; a0.y += xv0.y * rv0.y * n0;
                a0.z += xv0.z * rv0.z * n0; a0.w += xv0.w * rv0.w * n0;
            }
            a0.x += a1.x; a0.y += a1.y; a0.z += a1.z; a0.w += a1.w;
            a0.x += __shfl_down(a0.x, 32, 64);
            a0.y += __shfl_down(a0.y, 32, 64);
            a0.z += __shfl_down(a0.z, 32, 64);
            a0.w += __shfl_down(a0.w, 32, 64);
            if (sub == 0) {
                short4 sv;
                if (slot < 25) {
                    sv.x = f2bf(a0.x); sv.y = f2bf(a0.y);
                    sv.z = f2bf(a0.z); sv.w = f2bf(a0.w);
                } else {
                    sv.x = 0; sv.y = 0; sv.z = 0; sv.w = 0;
                }
                *reinterpret_cast<short4*>(dst + slot * 4) = sv;
            }
        } else if (sub == 0) {
            short4 z; z.x = 0; z.y = 0; z.z = 0; z.w = 0;
            *reinterpret_cast<short4*>(dst + slot * 4) = z;
        }
    }
    __syncthreads();

    // ---------- phase 2: MFMA over 12 k-steps; wave w handles nt = 2w, 2w+1 ----------
    int kg = lane >> 4;
    int cbase = lane & 15;
    int xrow = rbase + cbase;
    bool rowValid = (xrow < NE);
    const float* Arow = x + (size_t)(rowValid ? xrow : 0) * DIM;

    f32x4v acc0 = (f32x4v){0.f, 0.f, 0.f, 0.f};
    f32x4v acc1 = (f32x4v){0.f, 0.f, 0.f, 0.f};
    int nt0 = w * 2, nt1 = w * 2 + 1;

#pragma unroll
    for (int kstep = 0; kstep < 12; ++kstep) {
        short8v af;
        if (kstep < 8) {
            const short* srcp = (kstep < 4) ? Ain[cbase] : Aout[cbase];
            af = *reinterpret_cast<const short8v*>(srcp + (kstep & 3) * 32 + kg * 8);
        } else {
            int ks = kstep - 8;
            short8v a = (short8v){0, 0, 0, 0, 0, 0, 0, 0};
            if (rowValid) {
                if (ks < 3) {
                    int k0 = ks * 32 + kg * 8;
                    float4 lo = *reinterpret_cast<const float4*>(Arow + k0);
                    float4 hi = *reinterpret_cast<const float4*>(Arow + k0 + 4);
                    float4 l0 = *reinterpret_cast<const float4*>(loop_rel + k0);
                    float4 l1 = *reinterpret_cast<const float4*>(loop_rel + k0 + 4);
                    a[0] = f2bf(lo.x * l0.x); a[1] = f2bf(lo.y * l0.y);
                    a[2] = f2bf(lo.z * l0.z); a[3] = f2bf(lo.w * l0.w);
                    a[4] = f2bf(hi.x * l1.x); a[5] = f2bf(hi.y * l1.y);
                    a[6] = f2bf(hi.z * l1.z); a[7] = f2bf(hi.w * l1.w);
                } else if (kg == 0) {
                    float4 lo = *reinterpret_cast<const float4*>(Arow + 96);
                    float4 l0 = *reinterpret_cast<const float4*>(loop_rel + 96);
                    a[0] = f2bf(lo.x * l0.x); a[1] = f2bf(lo.y * l0.y);
                    a[2] = f2bf(lo.z * l0.z); a[3] = f2bf(lo.w * l0.w);
                }
            }
            af = a;
        }
        int fb = kstep * 7 * 64 + lane;
        short8v bf0 = reinterpret_cast<const short8v*>(wfrag)[fb + nt0 * 64];
        acc0 = __builtin_amdgcn_mfma_f32_16x16x32_bf16(af, bf0, acc0, 0, 0, 0);
        if (nt1 < 7) {
            short8v bf1 = reinterpret_cast<const short8v*>(wfrag)[fb + nt1 * 64];
            acc1 = __builtin_amdgcn_mfma_f32_16x16x32_bf16(af, bf1, acc1, 0, 0, 0);
        }
    }

    // ---------- epilogue: store + fused column stats ----------
#pragma unroll
    for (int t = 0; t < 2; ++t) {
        int nt = w * 2 + t;
        if (nt >= 7) break;
        f32x4v acc = t == 0 ? acc0 : acc1;
        int col = nt * 16 + cbase;
        if (col < DIM) {
            float ps = 0.f, pq = 0.f;
#pragma unroll
            for (int r = 0; r < 4; ++r) {
                int orow = rbase + kg * 4 + r;
                if (orow < NE) {
                    float v = acc[r];
                    out[(size_t)orow * DIM + col] = v;
                    ps += v; pq += v * v;
                }
            }
            atomicAdd(&cs[col], ps);
            atomicAdd(&cq[col], pq);
        }
    }
    __syncthreads();
    if (tid < DIM) {
        atomicAdd(&colsum[tid], cs[tid]);
        atomicAdd(&colsumsq[tid], cq[tid]);
    }
}

// ============ BN + tanh with inline finalize ============
__global__ void k_bn_tanh4(float* __restrict__ v, const float* __restrict__ colsum,
                           const float* __restrict__ colsumsq,
                           const float* __restrict__ gamma, const float* __restrict__ beta,
                           float invN, int total4) {
    int i = blockIdx.x * blockDim.x + threadIdx.x;
    if (i >= total4) return;
    int d = (i % 25) * 4;
    float4 val = reinterpret_cast<float4*>(v)[i];
    float4 sm = *reinterpret_cast<const float4*>(colsum + d);
    float4 sq = *reinterpret_cast<const float4*>(colsumsq + d);
    float4 g  = *reinterpret_cast<const float4*>(gamma + d);
    float4 b  = *reinterpret_cast<const float4*>(beta + d);
#define BNT(c) { float mu = sm.c * invN; float var = sq.c * invN - mu * mu;            \
                 if (var < 0.f) var = 0.f;                                             \
                 float s = rsqrtf(var * (1.0f / 9.0f) + BN_EPS) * (1.0f / 3.0f) * g.c; \
                 float t = b.c - mu * s;                                               \
                 val.c = tanhf(val.c * s + t); }
    BNT(x) BNT(y) BNT(z) BNT(w)
#undef BNT
    reinterpret_cast<float4*>(v)[i] = val;
}

extern "C" void kernel_launch(void* const* d_in, const int* in_sizes, int n_in,
                              void* d_out, int out_size, void* d_ws, size_t ws_size,
                              hipStream_t stream) {
    const float* x        = (const float*)d_in[0];
    const int*   ei       = (const int*)d_in[1];
    const int*   et       = (const int*)d_in[2];
    const float* rel      = (const float*)d_in[3];
    const float* w_in     = (const float*)d_in[4];
    const float* w_out    = (const float*)d_in[5];
    const float* w_loop   = (const float*)d_in[6];
    const float* w_rel    = (const float*)d_in[7];
    const float* loop_rel = (const float*)d_in[8];
    const float* gamma    = (const float*)d_in[10];
    const float* beta     = (const float*)d_in[11];

    const int NE = in_sizes[0] / DIM;     // 50000
    const int E  = in_sizes[2] / 2;       // 500000

    float* out  = (float*)d_out;
    float* out2 = out + (size_t)NE * DIM;
    const int relRows = in_sizes[3] / DIM;

    const int B = 256;
    const size_t twoNE = 2 * (size_t)NE;
    const int n = (int)twoNE;
    const int nb = (n + 1023) / 1024;
    const int WFRAG_SHORTS = 3 * 4 * 7 * 64 * 8;
    const int WFRAG_INTS = WFRAG_SHORTS / 2;

    // ws layout (ints):
    // hist[2NE] | colsum[128] colsumsq[128] | blocksum[128] blockoff[128]
    // | dinv[2NE] | base[2NE+16] | cursor[2NE] | wfrag[21504] | packed[2E]
    int* wsI = (int*)d_ws;
    int*   hist     = wsI;
    float* colsum   = (float*)(hist + twoNE);
    float* colsumsq = colsum + 128;
    int*   blocksum = (int*)(colsumsq + 128);
    int*   blockoff = blocksum + 128;
    float* dinv     = (float*)(blockoff + 128);
    int*   base     = (int*)(dinv + twoNE);
    int*   cursor   = base + twoNE + 16;
    short* wfrag    = (short*)(cursor + twoNE);
    unsigned int* packed = (unsigned int*)(cursor + twoNE + WFRAG_INTS);

    const int relTotal4 = relRows * (DIM / 4);
    const int nbW = (WPREP_THREADS + 255) / 256;
    const int nbR = (relTotal4 + 255) / 256;

    hipMemsetAsync(hist, 0, (twoNE + 256) * 4, stream);

    k_hist<<<1024, B, 0, stream>>>(ei, hist, E, NE);
    k_scanA<<<nb, B, 0, stream>>>(hist, base, blocksum, dinv, n);
    k_scanB<<<1, 256, 0, stream>>>(blocksum, blockoff, nb);
    k_scanC<<<nb, B, 0, stream>>>(base, cursor, blockoff, n, 2 * E);
    k_scatter<<<1024, B, 0, stream>>>(ei, et, cursor, packed, E, NE);
    k_wrel<<<nbW + nbR, B, 0, stream>>>(w_in, w_out, w_loop, wfrag,
                                        rel, w_rel, out2, nbW, relTotal4);
    k_fused<<<(NE + 15) / 16, B, 0, stream>>>(packed, base, x, rel, dinv, loop_rel,
                                              wfrag, out, colsum, colsumsq, NE);

    int total4 = NE * (DIM / 4);
    k_bn_tanh4<<<(total4 + B - 1) / B, B, 0, stream>>>(out, colsum, colsumsq,
                                                       gamma, beta, 1.0f / NE, total4);
}